// Round 16
// baseline (289.785 us; speedup 1.0000x reference)
//
#include <hip/hip_runtime.h>
#include <hip/hip_bf16.h>
#include <math.h>

#define DIMV 256
#define DV 32
#define QKVS 768   // interleaved row stride: q[256] | k[256] | v[256]

typedef __attribute__((ext_vector_type(8))) short bf16x8;
typedef __attribute__((ext_vector_type(4))) float f32x4;

#define EXPS(x) __expf(x)
#define SCORE_SCALE 0.17677669529663687f

static __device__ __forceinline__ unsigned short f2bf(float f) {
    unsigned x = __float_as_uint(f);
    x += 0x7FFF + ((x >> 16) & 1);   // round-to-nearest-even
    return (unsigned short)(x >> 16);
}
static __device__ __forceinline__ float bf2f(unsigned short u) {
    return __uint_as_float(((unsigned)u) << 16);
}

// ------ weight f32 -> bf16 into FRAGMENT-MAJOR step order + fused degree count ------
// (R15-verified) Wcat per matrix m: [h:2][k:8][frag:512], frag f = n*64+kg*16+col
// holds W_m[h*128+n*16+col][k*32+kg*8 .. +8] as bf16x8 (16B).

__global__ void cvt_w_count(const float* __restrict__ Wq, const float* __restrict__ Wk,
                            const float* __restrict__ Wv, const float* __restrict__ Wo,
                            unsigned short* __restrict__ Wcat,
                            const int* __restrict__ dst, int* __restrict__ deg, int E) {
    int g = blockIdx.x * 256 + threadIdx.x;      // frag id, 4*8192 total
    int m = g >> 13;
    const float* W = m == 0 ? Wq : m == 1 ? Wk : m == 2 ? Wv : Wo;
    int r = g & 8191;
    int h = r >> 12, k = (r >> 9) & 7, f = r & 511;
    int n = f >> 6, kg = (f >> 4) & 3, col = f & 15;
    int c = h * 128 + n * 16 + col;
    int koff = k * 32 + kg * 8;
    const float* src = W + c * 256 + koff;
    float4 f0 = *(const float4*)src;
    float4 f1 = *(const float4*)(src + 4);
    bf16x8 o;
    o[0] = (short)f2bf(f0.x); o[1] = (short)f2bf(f0.y);
    o[2] = (short)f2bf(f0.z); o[3] = (short)f2bf(f0.w);
    o[4] = (short)f2bf(f1.x); o[5] = (short)f2bf(f1.y);
    o[6] = (short)f2bf(f1.z); o[7] = (short)f2bf(f1.w);
    *(bf16x8*)(Wcat + (size_t)g * 8) = o;

    int nthr = gridDim.x * 256;
    for (int e = g; e < E; e += nthr) atomicAdd(&deg[dst[e]], 1);
}

// ---------------- CSR scan (R3 config — measured fast) ----------------

__global__ void zero_i32(int* __restrict__ p, int n) {
    int i = blockIdx.x * blockDim.x + threadIdx.x;
    if (i < n) p[i] = 0;
}

__global__ void block_sum(const int* __restrict__ deg, int* __restrict__ bsum, int n) {
    __shared__ int sm[256];
    int i = blockIdx.x * 256 + threadIdx.x;
    sm[threadIdx.x] = (i < n) ? deg[i] : 0;
    __syncthreads();
    for (int s = 128; s > 0; s >>= 1) {
        if (threadIdx.x < s) sm[threadIdx.x] += sm[threadIdx.x + s];
        __syncthreads();
    }
    if (threadIdx.x == 0) bsum[blockIdx.x] = sm[0];
}

__global__ void scan_bsum(int* __restrict__ bsum, int nb) {
    if (threadIdx.x == 0) {
        int r = 0;
        for (int i = 0; i < nb; ++i) { int v = bsum[i]; bsum[i] = r; r += v; }
    }
}

__global__ void scan_final(const int* __restrict__ deg, const int* __restrict__ bsum,
                           int* __restrict__ offsets, int* __restrict__ cursor, int n) {
    __shared__ int sm[256];
    int i = blockIdx.x * 256 + threadIdx.x;
    int v = (i < n) ? deg[i] : 0;
    sm[threadIdx.x] = v;
    __syncthreads();
    for (int s = 1; s < 256; s <<= 1) {
        int t = (threadIdx.x >= s) ? sm[threadIdx.x - s] : 0;
        __syncthreads();
        sm[threadIdx.x] += t;
        __syncthreads();
    }
    int excl = sm[threadIdx.x] - v + bsum[blockIdx.x];
    if (i < n) { offsets[i] = excl; cursor[i] = excl; }
    if (i == n - 1) offsets[n] = excl + v;
}

// -------- R16: barrier-free register-streaming GEMM --------
// Block = 64 rows x 4 waves (2 row-halves x 2 col-halves). A strip in registers
// (loaded once, fused f32->bf16). B fragments stream L2 -> registers directly:
// per step 4x global_load_dwordx4 at wb + s*8192 + lane*16 (contiguous 1KB/wave,
// Wcat is fragment-major so this is both coalesced and layout-exact). 3-deep
// rotating register buffer b[s%3][4], consume-then-refill, fully unrolled so all
// indices are compile-time (rule #20). ZERO barriers / cross-wave LDS / manual
// waitcnt — compiler's per-register vmcnt tracking orders loads before MFMA use.
// LDS only for the wave-private bf16 transpose epilogue (no sync needed beyond
// wave-private lgkmcnt).

template<bool AF32, bool OF32, int NCT, int OSTRIDE, bool SCATTER>
__global__ __launch_bounds__(256)
void gemm_stream(const void* __restrict__ Ain,
                 const unsigned short* __restrict__ Wb,
                 const float* __restrict__ b0, const float* __restrict__ b1,
                 const float* __restrict__ b2,
                 void* __restrict__ Cout, int M, int scb,
                 const int* __restrict__ esrc, const int* __restrict__ edst,
                 int* __restrict__ cursor, int* __restrict__ perm_src, int E) {
    if (SCATTER && (int)blockIdx.x < scb) {
        int nthr = scb * 256;
        for (int e = (int)blockIdx.x * 256 + (int)threadIdx.x; e < E; e += nthr)
            perm_src[atomicAdd(&cursor[edst[e]], 1)] = esrc[e];
        return;
    }
    __shared__ unsigned short Tls[4][32][68];   // per-wave transpose (17 KB)

    const int bid = (int)blockIdx.x - (SCATTER ? scb : 0);
    const int tid = threadIdx.x, w = tid >> 6, lane = tid & 63;
    const int wr = w >> 1, wc = w & 1;
    const int lrow = lane & 15, lkg = lane >> 4;
    const int row0 = bid * 64;
    const int STOT = NCT * 8;

    // A strip -> registers (32 rows/wave x K=256), fused f32->bf16
    bf16x8 a[2][8];
    #pragma unroll
    for (int m = 0; m < 2; ++m) {
        int arow = min(row0 + wr * 32 + m * 16 + lrow, M - 1);
        if (AF32) {
            const float* ap = (const float*)Ain + (size_t)arow * DIMV + lkg * 8;
            #pragma unroll
            for (int k = 0; k < 8; ++k) {
                float4 f0 = *(const float4*)(ap + k * 32);
                float4 f1 = *(const float4*)(ap + k * 32 + 4);
                bf16x8 r;
                r[0] = (short)f2bf(f0.x); r[1] = (short)f2bf(f0.y);
                r[2] = (short)f2bf(f0.z); r[3] = (short)f2bf(f0.w);
                r[4] = (short)f2bf(f1.x); r[5] = (short)f2bf(f1.y);
                r[6] = (short)f2bf(f1.z); r[7] = (short)f2bf(f1.w);
                a[m][k] = r;
            }
        } else {
            const unsigned short* ap = (const unsigned short*)Ain + (size_t)arow * DIMV + lkg * 8;
            #pragma unroll
            for (int k = 0; k < 8; ++k)
                a[m][k] = *(const bf16x8*)(ap + k * 32);
        }
    }

    // B streaming base: this wave's 4 n-blocks (wc selects upper/lower 64 cols)
    const char* wbase = (const char*)Wb + (size_t)(wc * 4) * 1024 + (size_t)lane * 16;

    bf16x8 b[3][4];
    #pragma unroll
    for (int j = 0; j < 3; ++j) {
        const char* p = wbase + (size_t)j * 8192;
        #pragma unroll
        for (int n = 0; n < 4; ++n)
            b[j][n] = *(const bf16x8*)(p + n * 1024);
    }

    #pragma unroll
    for (int ct = 0; ct < NCT; ++ct) {
        f32x4 acc[2][4] = {};
        #pragma unroll
        for (int k = 0; k < 8; ++k) {
            const int s = ct * 8 + k;
            #pragma unroll
            for (int n = 0; n < 4; ++n) {
                acc[0][n] = __builtin_amdgcn_mfma_f32_16x16x32_bf16(a[0][k], b[s % 3][n], acc[0][n], 0, 0, 0);
                acc[1][n] = __builtin_amdgcn_mfma_f32_16x16x32_bf16(a[1][k], b[s % 3][n], acc[1][n], 0, 0, 0);
            }
            if (s + 3 < STOT) {      // refill the buffer just consumed (WAR on regs)
                const char* p = wbase + (size_t)(s + 3) * 8192;
                #pragma unroll
                for (int n = 0; n < 4; ++n)
                    b[s % 3][n] = *(const bf16x8*)(p + n * 1024);
            }
        }

        // ---- epilogue for col-tile ct ----
        if (OF32) {
            #pragma unroll
            for (int n = 0; n < 4; ++n) {
                int c = ct * 128 + wc * 64 + n * 16 + lrow;
                const float* bp = (c >> 8) == 0 ? b0 : ((c >> 8) == 1 ? b1 : b2);
                float bias = bp[c & 255];
                #pragma unroll
                for (int m = 0; m < 2; ++m)
                    #pragma unroll
                    for (int r = 0; r < 4; ++r) {
                        int grow = row0 + wr * 32 + m * 16 + lkg * 4 + r;
                        if (grow < M)
                            ((float*)Cout)[(size_t)grow * OSTRIDE + c] = acc[m][n][r] + bias;
                    }
            }
        } else {
            // per-wave LDS transpose -> coalesced 16B stores (full cache lines)
            #pragma unroll
            for (int n = 0; n < 4; ++n) {
                int c = ct * 128 + wc * 64 + n * 16 + lrow;
                const float* bp = (c >> 8) == 0 ? b0 : ((c >> 8) == 1 ? b1 : b2);
                float bias = bp[c & 255];
                #pragma unroll
                for (int m = 0; m < 2; ++m)
                    #pragma unroll
                    for (int r = 0; r < 4; ++r)
                        Tls[w][m * 16 + lkg * 4 + r][n * 16 + lrow] = f2bf(acc[m][n][r] + bias);
            }
            asm volatile("s_waitcnt lgkmcnt(0)" ::: "memory");   // wave-private
            #pragma unroll
            for (int j = 0; j < 4; ++j) {
                int rloc = j * 8 + (lane >> 3);
                bf16x8 v = *(const bf16x8*)(&Tls[w][rloc][(lane & 7) * 8]);
                int grow = row0 + wr * 32 + rloc;
                if (grow < M)
                    *(bf16x8*)((unsigned short*)Cout + (size_t)grow * OSTRIDE +
                               ct * 128 + wc * 64 + (lane & 7) * 8) = v;
            }
            asm volatile("s_waitcnt lgkmcnt(0)" ::: "memory");   // reads done before next ct overwrites
        }
    }
}

// ---------------- per-node edge-softmax attention (R12-frozen) ----------------

__global__ __launch_bounds__(256)
void node_attn(const unsigned short* __restrict__ QKV,
               const int* __restrict__ offsets, const int* __restrict__ perm_src,
               unsigned short* __restrict__ attn, int N) {
    int wid = blockIdx.x * (blockDim.x >> 6) + (threadIdx.x >> 6);
    if (wid >= N) return;
    int lane = threadIdx.x & 63;
    unsigned col = (unsigned)((lane >> 3) * DV + (lane & 7) * 4);

    ushort4 kr = *(const ushort4*)(QKV + (size_t)wid * QKVS + 256 + col);
    float k0 = bf2f(kr.x) * SCORE_SCALE, k1 = bf2f(kr.y) * SCORE_SCALE;
    float k2 = bf2f(kr.z) * SCORE_SCALE, k3 = bf2f(kr.w) * SCORE_SCALE;

    float mA = -INFINITY, lA = 0.f, aA0 = 0.f, aA1 = 0.f, aA2 = 0.f, aA3 = 0.f;
    float mB = -INFINITY, lB = 0.f, aB0 = 0.f, aB1 = 0.f, aB2 = 0.f, aB3 = 0.f;

    auto upd = [&](ushort4 qr, ushort4 vr, float& m, float& l,
                   float& a0, float& a1, float& a2, float& a3) {
        float d = bf2f(qr.x) * k0 + bf2f(qr.y) * k1 + bf2f(qr.z) * k2 + bf2f(qr.w) * k3;
        d += __shfl_xor(d, 1); d += __shfl_xor(d, 2); d += __shfl_xor(d, 4);
        float mn = fmaxf(m, d);
        float sc = EXPS(m - mn);
        float pe = EXPS(d - mn);
        l = l * sc + pe;
        a0 = a0 * sc + pe * bf2f(vr.x);
        a1 = a1 * sc + pe * bf2f(vr.y);
        a2 = a2 * sc + pe * bf2f(vr.z);
        a3 = a3 * sc + pe * bf2f(vr.w);
        m = mn;
    };

    int e0 = offsets[wid], e1 = offsets[wid + 1];
    int rem = e1 - e0;
    int S = rem >> 1;
    int p = e0;

    if (S >= 1) {
        unsigned o0 = (unsigned)perm_src[p] * QKVS + col;
        unsigned o1 = (unsigned)perm_src[p + 1] * QKVS + col;
        ushort4 qA0 = *(const ushort4*)(QKV + o0);
        ushort4 vA0 = *(const ushort4*)(QKV + o0 + 512);
        ushort4 qA1 = *(const ushort4*)(QKV + o1);
        ushort4 vA1 = *(const ushort4*)(QKV + o1 + 512);
        unsigned n0 = 0, n1 = 0;
        if (S >= 2) {
            n0 = (unsigned)perm_src[p + 2] * QKVS + col;
            n1 = (unsigned)perm_src[p + 3] * QKVS + col;
        }
        ushort4 qB0, qB1, vB0, vB1;

        int s = 0;
        while (s + 2 <= S) {
            qB0 = *(const ushort4*)(QKV + n0);
            vB0 = *(const ushort4*)(QKV + n0 + 512);
            qB1 = *(const ushort4*)(QKV + n1);
            vB1 = *(const ushort4*)(QKV + n1 + 512);
            if (s + 2 < S) {
                n0 = (unsigned)perm_src[p + 2 * s + 4] * QKVS + col;
                n1 = (unsigned)perm_src[p + 2 * s + 5] * QKVS + col;
            }
            upd(qA0, vA0, mA, lA, aA0, aA1, aA2, aA3);
            upd(qA1, vA1, mB, lB, aB0, aB1, aB2, aB3);

            if (s + 2 < S) {
                qA0 = *(const ushort4*)(QKV + n0);
                vA0 = *(const ushort4*)(QKV + n0 + 512);
                qA1 = *(const ushort4*)(QKV + n1);
                vA1 = *(const ushort4*)(QKV + n1 + 512);
                if (s + 3 < S) {
                    n0 = (unsigned)perm_src[p + 2 * s + 6] * QKVS + col;
                    n1 = (unsigned)perm_src[p + 2 * s + 7] * QKVS + col;
                }
            }
            upd(qB0, vB0, mA, lA, aA0, aA1, aA2, aA3);
            upd(qB1, vB1, mB, lB, aB0, aB1, aB2, aB3);
            s += 2;
        }
        if (s < S) {
            upd(qA0, vA0, mA, lA, aA0, aA1, aA2, aA3);
            upd(qA1, vA1, mB, lB, aB0, aB1, aB2, aB3);
        }
    }
    if (rem & 1) {
        unsigned o0 = (unsigned)perm_src[e1 - 1] * QKVS + col;
        ushort4 q0 = *(const ushort4*)(QKV + o0);
        ushort4 v0 = *(const ushort4*)(QKV + o0 + 512);
        upd(q0, v0, mA, lA, aA0, aA1, aA2, aA3);
    }

    float mn = fmaxf(mA, mB);
    float scA = (lA > 0.f) ? EXPS(mA - mn) : 0.f;
    float scB = (lB > 0.f) ? EXPS(mB - mn) : 0.f;
    float l = lA * scA + lB * scB;
    float o0 = aA0 * scA + aB0 * scB;
    float o1 = aA1 * scA + aB1 * scB;
    float o2 = aA2 * scA + aB2 * scB;
    float o3 = aA3 * scA + aB3 * scB;
    float inv = (l > 0.f) ? 1.f / l : 0.f;

    ushort4 o;
    o.x = f2bf(o0 * inv); o.y = f2bf(o1 * inv); o.z = f2bf(o2 * inv); o.w = f2bf(o3 * inv);
    *(ushort4*)(attn + (size_t)wid * DIMV + col) = o;
}

// ---------------- launcher ----------------

extern "C" void kernel_launch(void* const* d_in, const int* in_sizes, int n_in,
                              void* d_out, int out_size, void* d_ws, size_t ws_size,
                              hipStream_t stream) {
    const float* x  = (const float*)d_in[0];
    const float* Wq = (const float*)d_in[1];
    const float* bq = (const float*)d_in[2];
    const float* Wk = (const float*)d_in[3];
    const float* bk = (const float*)d_in[4];
    const float* Wv = (const float*)d_in[5];
    const float* bv = (const float*)d_in[6];
    const float* Wo = (const float*)d_in[7];
    const float* bo = (const float*)d_in[8];
    const int* src  = (const int*)d_in[9];
    const int* dst  = (const int*)d_in[10];
    int N = in_sizes[0] / DIMV;
    int E = in_sizes[9];
    float* out = (float*)d_out;

    char* p = (char*)d_ws;
    auto alloc = [&](size_t bytes) {
        char* r = p;
        p += (bytes + 255) & ~(size_t)255;
        return r;
    };
    unsigned short* Wcat = (unsigned short*)alloc((size_t)4 * 65536 * 2);   // fragment-major
    unsigned short* QKV  = (unsigned short*)alloc((size_t)N * QKVS * 2);    // interleaved q|k|v
    unsigned short* attn = (unsigned short*)alloc((size_t)N * DIMV * 2);
    int* deg             = (int*)alloc((size_t)N * 4);
    int* offsets         = (int*)alloc((size_t)(N + 1) * 4);
    int* cursor          = (int*)alloc((size_t)N * 4);
    int* perm_src        = (int*)alloc((size_t)E * 4);
    int* bsum            = (int*)alloc((size_t)1024 * 4);

    int nb = (N + 255) / 256;
    zero_i32<<<nb, 256, 0, stream>>>(deg, N);

    // weight conversion into fragment-major order + fused degree count
    cvt_w_count<<<128, 256, 0, stream>>>(Wq, Wk, Wv, Wo, Wcat, dst, deg, E);

    // scan: deg -> offsets/cursor
    block_sum<<<nb, 256, 0, stream>>>(deg, bsum, N);
    scan_bsum<<<1, 64, 0, stream>>>(bsum, nb);
    scan_final<<<nb, 256, 0, stream>>>(deg, bsum, offsets, cursor, N);

    // QKV projection (barrier-free streaming) + leading scatter blocks
    int rblocks = (N + 63) / 64;
    const int SCB = 160;
    gemm_stream<true, false, 6, QKVS, true><<<SCB + rblocks, 256, 0, stream>>>(
        x, Wcat, bq, bk, bv, QKV, N, SCB, src, dst, cursor, perm_src, E);

    node_attn<<<(N + 3) / 4, 256, 0, stream>>>(QKV, offsets, perm_src, attn, N);

    // output projection: attn(bf16) -> out(f32)
    gemm_stream<false, true, 2, DIMV, false><<<rblocks, 256, 0, stream>>>(
        attn, Wcat + (size_t)3 * 65536, bo, bo, bo, out, N, 0,
        nullptr, nullptr, nullptr, nullptr, 0);
}

// Round 17
// 268.755 us; speedup vs baseline: 1.0782x; 1.0782x over previous
//
#include <hip/hip_runtime.h>
#include <hip/hip_bf16.h>
#include <math.h>

#define DIMV 256
#define DV 32
#define QKVS 768   // interleaved row stride: q[256] | k[256] | v[256]

typedef __attribute__((ext_vector_type(8))) short bf16x8;
typedef __attribute__((ext_vector_type(4))) float f32x4;

#define EXPS(x) __expf(x)
#define SCORE_SCALE 0.17677669529663687f

static __device__ __forceinline__ unsigned short f2bf(float f) {
    unsigned x = __float_as_uint(f);
    x += 0x7FFF + ((x >> 16) & 1);   // round-to-nearest-even
    return (unsigned short)(x >> 16);
}
static __device__ __forceinline__ float bf2f(unsigned short u) {
    return __uint_as_float(((unsigned)u) << 16);
}

static __device__ __forceinline__ void async16(const void* g, void* lds) {
    __builtin_amdgcn_global_load_lds(
        (const __attribute__((address_space(1))) void*)g,
        (__attribute__((address_space(3))) void*)lds, 16, 0, 0);
}

// load-count-based vmcnt: n = number of LOADS issued after the load we need.
// Loads retire in order among themselves (m135); stores in the queue only
// lengthen the wait, never make it unsafe.
static __device__ __forceinline__ void waitvm(int n) {
    switch (n) {
    case 0: asm volatile("s_waitcnt vmcnt(0)" ::: "memory"); break;
    case 2: asm volatile("s_waitcnt vmcnt(2)" ::: "memory"); break;
    default: asm volatile("s_waitcnt vmcnt(4)" ::: "memory"); break;
    }
}

// ------ weight f32 -> bf16 into FRAGMENT-MAJOR step order + fused degree count ------
// Wcat per matrix m: [h:2][k:8][frag:512] where frag f = n*64 + kg*16 + col holds
// W_m[h*128 + n*16 + col][k*32 + kg*8 .. +8] as bf16x8 (16B).
// => gemm staging source offset == LDS dest offset == linear: DMA is perfectly
// coalesced (1KB/wave contiguous) AND the ds_read is identity (conflict-free).
// The transpose cost is paid ONCE here on 512KB, not per K-step in the GEMM.

__global__ void cvt_w_count(const float* __restrict__ Wq, const float* __restrict__ Wk,
                            const float* __restrict__ Wv, const float* __restrict__ Wo,
                            unsigned short* __restrict__ Wcat,
                            const int* __restrict__ dst, int* __restrict__ deg, int E) {
    int g = blockIdx.x * 256 + threadIdx.x;      // frag id, 4*8192 total
    int m = g >> 13;
    const float* W = m == 0 ? Wq : m == 1 ? Wk : m == 2 ? Wv : Wo;
    int r = g & 8191;
    int h = r >> 12, k = (r >> 9) & 7, f = r & 511;
    int n = f >> 6, kg = (f >> 4) & 3, col = f & 15;
    int c = h * 128 + n * 16 + col;
    int koff = k * 32 + kg * 8;
    const float* src = W + c * 256 + koff;
    float4 f0 = *(const float4*)src;
    float4 f1 = *(const float4*)(src + 4);
    bf16x8 o;
    o[0] = (short)f2bf(f0.x); o[1] = (short)f2bf(f0.y);
    o[2] = (short)f2bf(f0.z); o[3] = (short)f2bf(f0.w);
    o[4] = (short)f2bf(f1.x); o[5] = (short)f2bf(f1.y);
    o[6] = (short)f2bf(f1.z); o[7] = (short)f2bf(f1.w);
    *(bf16x8*)(Wcat + (size_t)g * 8) = o;

    // fused degree count (grid-stride over E)
    int nthr = gridDim.x * 256;
    for (int e = g; e < E; e += nthr) atomicAdd(&deg[dst[e]], 1);
}

// ---------------- CSR scan (R3 config — measured fast) ----------------

__global__ void zero_i32(int* __restrict__ p, int n) {
    int i = blockIdx.x * blockDim.x + threadIdx.x;
    if (i < n) p[i] = 0;
}

__global__ void block_sum(const int* __restrict__ deg, int* __restrict__ bsum, int n) {
    __shared__ int sm[256];
    int i = blockIdx.x * 256 + threadIdx.x;
    sm[threadIdx.x] = (i < n) ? deg[i] : 0;
    __syncthreads();
    for (int s = 128; s > 0; s >>= 1) {
        if (threadIdx.x < s) sm[threadIdx.x] += sm[threadIdx.x + s];
        __syncthreads();
    }
    if (threadIdx.x == 0) bsum[blockIdx.x] = sm[0];
}

__global__ void scan_bsum(int* __restrict__ bsum, int nb) {
    if (threadIdx.x == 0) {
        int r = 0;
        for (int i = 0; i < nb; ++i) { int v = bsum[i]; bsum[i] = r; r += v; }
    }
}

__global__ void scan_final(const int* __restrict__ deg, const int* __restrict__ bsum,
                           int* __restrict__ offsets, int* __restrict__ cursor, int n) {
    __shared__ int sm[256];
    int i = blockIdx.x * 256 + threadIdx.x;
    int v = (i < n) ? deg[i] : 0;
    sm[threadIdx.x] = v;
    __syncthreads();
    for (int s = 1; s < 256; s <<= 1) {
        int t = (threadIdx.x >= s) ? sm[threadIdx.x - s] : 0;
        __syncthreads();
        sm[threadIdx.x] += t;
        __syncthreads();
    }
    int excl = sm[threadIdx.x] - v + bsum[blockIdx.x];
    if (i < n) { offsets[i] = excl; cursor[i] = excl; }
    if (i == n - 1) offsets[n] = excl + v;
}

// -------- long-pipeline reg-A GEMM (R15-verified best: pre-permuted W, linear DMA) ----
// Wb is fragment-major (see cvt_w_count): stage(s) source == dest == linear,
// ds_read identity (base + n*1024 + lane*16) — both coalesced and conflict-free.
// Counted vmcnt (store-agnostic); ds_read -> lgkmcnt(0) -> sched_barrier(0) -> MFMA
// pin (rule #18) prevents the R10/R11 cross-barrier read race.

template<bool AF32, bool OF32, int NCT, int OSTRIDE, bool SCATTER>
__global__ __launch_bounds__(256)
void gemm_reg(const void* __restrict__ Ain,
              const unsigned short* __restrict__ Wb,
              const float* __restrict__ b0, const float* __restrict__ b1,
              const float* __restrict__ b2,
              void* __restrict__ Cout, int M, int scb,
              const int* __restrict__ esrc, const int* __restrict__ edst,
              int* __restrict__ cursor, int* __restrict__ perm_src, int E) {
    if (SCATTER && (int)blockIdx.x < scb) {
        int nthr = scb * 256;
        for (int e = (int)blockIdx.x * 256 + (int)threadIdx.x; e < E; e += nthr)
            perm_src[atomicAdd(&cursor[edst[e]], 1)] = esrc[e];
        return;
    }
    __shared__ unsigned short Bls[4][4096];     // 4 x 8KB B-step ring
    __shared__ unsigned short Tls[4 * 2176];    // transpose: 4 waves x 16 x 136 shorts
    __shared__ float BiasLds[NCT * 128];

    const int bid = (int)blockIdx.x - (SCATTER ? scb : 0);
    const int tid = threadIdx.x, w = tid >> 6, lane = tid & 63;
    const int lrow = lane & 15, lkg = lane >> 4;
    const int row0 = bid * 64;
    const int STOT = NCT * 8;

    // biases -> LDS
    for (int i = tid; i < NCT * 128; i += 256) {
        int mat = i >> 8;
        const float* bp = mat == 0 ? b0 : (mat == 1 ? b1 : b2);
        BiasLds[i] = bp[i & 255];
    }

    // staging: source == dest == linear (W pre-permuted at cvt time)
    auto stage = [&](int s) {
        const char* gsrc = (const char*)Wb + (size_t)s * 8192 + w * 2048 + lane * 16;
        #pragma unroll
        for (int j = 0; j < 2; ++j)
            async16(gsrc + j * 1024, (char*)&Bls[s & 3][0] + (w * 2048 + j * 1024));
    };
    stage(0); stage(1); stage(2);

    // A strip -> registers (16 rows/wave x K=256), fused f32->bf16
    bf16x8 a[8];
    {
        int arow = min(row0 + w * 16 + lrow, M - 1);
        if (AF32) {
            const float* ap = (const float*)Ain + (size_t)arow * DIMV + lkg * 8;
            #pragma unroll
            for (int k = 0; k < 8; ++k) {
                float4 f0 = *(const float4*)(ap + k * 32);
                float4 f1 = *(const float4*)(ap + k * 32 + 4);
                bf16x8 r;
                r[0] = (short)f2bf(f0.x); r[1] = (short)f2bf(f0.y);
                r[2] = (short)f2bf(f0.z); r[3] = (short)f2bf(f0.w);
                r[4] = (short)f2bf(f1.x); r[5] = (short)f2bf(f1.y);
                r[6] = (short)f2bf(f1.z); r[7] = (short)f2bf(f1.w);
                a[k] = r;
            }
        } else {
            const unsigned short* ap = (const unsigned short*)Ain + (size_t)arow * DIMV + lkg * 8;
            #pragma unroll
            for (int k = 0; k < 8; ++k)
                a[k] = *(const bf16x8*)(ap + k * 32);
        }
    }

    asm volatile("s_waitcnt vmcnt(0) lgkmcnt(0)" ::: "memory");
    __builtin_amdgcn_s_barrier();

    #pragma unroll
    for (int ct = 0; ct < NCT; ++ct) {
        f32x4 acc[8] = {};
        #pragma unroll
        for (int k = 0; k < 8; ++k) {
            const int s = ct * 8 + k;
            if (s == STOT - 1)      waitvm(0);
            else if (s == STOT - 2) waitvm(2);
            else                    waitvm(4);   // D(s) retired (store-agnostic)
            __builtin_amdgcn_s_barrier();        // all waves' D(s) in LDS; all prior
                                                 // reads of the overwrite target retired
            if (s + 3 < STOT) stage(s + 3);
            asm volatile("" ::: "memory");

            const char* base = (const char*)&Bls[s & 3][0];
            bf16x8 bF[8];
            #pragma unroll
            for (int n = 0; n < 8; ++n)
                bF[n] = *(const bf16x8*)(base + n * 1024 + lane * 16);   // identity, 0-conflict
            asm volatile("s_waitcnt lgkmcnt(0)" ::: "memory");  // reads retired
            __builtin_amdgcn_sched_barrier(0);                  // pin (rule #18)
            #pragma unroll
            for (int n = 0; n < 8; ++n)
                acc[n] = __builtin_amdgcn_mfma_f32_16x16x32_bf16(a[k], bF[n], acc[n], 0, 0, 0);
        }
        asm volatile("" ::: "memory");

        // ---- epilogue for col-tile ct (output cols ct*128..ct*128+128) ----
        if (OF32) {
            #pragma unroll
            for (int n = 0; n < 8; ++n) {
                float bias = BiasLds[ct * 128 + n * 16 + lrow];
                #pragma unroll
                for (int r = 0; r < 4; ++r) {
                    int grow = row0 + w * 16 + lkg * 4 + r;
                    if (grow < M)
                        ((float*)Cout)[(size_t)grow * OSTRIDE + ct * 128 + n * 16 + lrow] =
                            acc[n][r] + bias;
                }
            }
        } else {
            // per-wave LDS transpose -> coalesced b128 stores (full cache lines)
            #pragma unroll
            for (int n = 0; n < 8; ++n) {
                float bias = BiasLds[ct * 128 + n * 16 + lrow];
                #pragma unroll
                for (int r = 0; r < 4; ++r)
                    Tls[w * 2176 + (lkg * 4 + r) * 136 + n * 16 + lrow] =
                        f2bf(acc[n][r] + bias);
            }
            asm volatile("s_waitcnt lgkmcnt(0)" ::: "memory");  // Tls writes done (wave-private)
            #pragma unroll
            for (int j = 0; j < 4; ++j) {
                int srow = j * 4 + lkg;
                bf16x8 v = *(const bf16x8*)(&Tls[w * 2176 + srow * 136 + lrow * 8]);
                int grow = row0 + w * 16 + srow;
                if (grow < M)
                    *(bf16x8*)((unsigned short*)Cout + (size_t)grow * OSTRIDE +
                               ct * 128 + lrow * 8) = v;
            }
        }
        asm volatile("" ::: "memory");
    }
}

// ---------------- per-node edge-softmax attention (R12-frozen, single dispatch) ----

__global__ __launch_bounds__(256)
void node_attn(const unsigned short* __restrict__ QKV,
               const int* __restrict__ offsets, const int* __restrict__ perm_src,
               unsigned short* __restrict__ attn, int N) {
    int wid = blockIdx.x * (blockDim.x >> 6) + (threadIdx.x >> 6);
    if (wid >= N) return;
    int lane = threadIdx.x & 63;
    unsigned col = (unsigned)((lane >> 3) * DV + (lane & 7) * 4);

    ushort4 kr = *(const ushort4*)(QKV + (size_t)wid * QKVS + 256 + col);
    float k0 = bf2f(kr.x) * SCORE_SCALE, k1 = bf2f(kr.y) * SCORE_SCALE;
    float k2 = bf2f(kr.z) * SCORE_SCALE, k3 = bf2f(kr.w) * SCORE_SCALE;

    float mA = -INFINITY, lA = 0.f, aA0 = 0.f, aA1 = 0.f, aA2 = 0.f, aA3 = 0.f;
    float mB = -INFINITY, lB = 0.f, aB0 = 0.f, aB1 = 0.f, aB2 = 0.f, aB3 = 0.f;

    auto upd = [&](ushort4 qr, ushort4 vr, float& m, float& l,
                   float& a0, float& a1, float& a2, float& a3) {
        float d = bf2f(qr.x) * k0 + bf2f(qr.y) * k1 + bf2f(qr.z) * k2 + bf2f(qr.w) * k3;
        d += __shfl_xor(d, 1); d += __shfl_xor(d, 2); d += __shfl_xor(d, 4);
        float mn = fmaxf(m, d);
        float sc = EXPS(m - mn);
        float pe = EXPS(d - mn);
        l = l * sc + pe;
        a0 = a0 * sc + pe * bf2f(vr.x);
        a1 = a1 * sc + pe * bf2f(vr.y);
        a2 = a2 * sc + pe * bf2f(vr.z);
        a3 = a3 * sc + pe * bf2f(vr.w);
        m = mn;
    };

    int e0 = offsets[wid], e1 = offsets[wid + 1];
    int rem = e1 - e0;
    int S = rem >> 1;
    int p = e0;

    if (S >= 1) {
        unsigned o0 = (unsigned)perm_src[p] * QKVS + col;
        unsigned o1 = (unsigned)perm_src[p + 1] * QKVS + col;
        ushort4 qA0 = *(const ushort4*)(QKV + o0);
        ushort4 vA0 = *(const ushort4*)(QKV + o0 + 512);
        ushort4 qA1 = *(const ushort4*)(QKV + o1);
        ushort4 vA1 = *(const ushort4*)(QKV + o1 + 512);
        unsigned n0 = 0, n1 = 0;
        if (S >= 2) {
            n0 = (unsigned)perm_src[p + 2] * QKVS + col;
            n1 = (unsigned)perm_src[p + 3] * QKVS + col;
        }
        ushort4 qB0, qB1, vB0, vB1;

        int s = 0;
        while (s + 2 <= S) {
            qB0 = *(const ushort4*)(QKV + n0);
            vB0 = *(const ushort4*)(QKV + n0 + 512);
            qB1 = *(const ushort4*)(QKV + n1);
            vB1 = *(const ushort4*)(QKV + n1 + 512);
            if (s + 2 < S) {
                n0 = (unsigned)perm_src[p + 2 * s + 4] * QKVS + col;
                n1 = (unsigned)perm_src[p + 2 * s + 5] * QKVS + col;
            }
            upd(qA0, vA0, mA, lA, aA0, aA1, aA2, aA3);
            upd(qA1, vA1, mB, lB, aB0, aB1, aB2, aB3);

            if (s + 2 < S) {
                qA0 = *(const ushort4*)(QKV + n0);
                vA0 = *(const ushort4*)(QKV + n0 + 512);
                qA1 = *(const ushort4*)(QKV + n1);
                vA1 = *(const ushort4*)(QKV + n1 + 512);
                if (s + 3 < S) {
                    n0 = (unsigned)perm_src[p + 2 * s + 6] * QKVS + col;
                    n1 = (unsigned)perm_src[p + 2 * s + 7] * QKVS + col;
                }
            }
            upd(qB0, vB0, mA, lA, aA0, aA1, aA2, aA3);
            upd(qB1, vB1, mB, lB, aB0, aB1, aB2, aB3);
            s += 2;
        }
        if (s < S) {
            upd(qA0, vA0, mA, lA, aA0, aA1, aA2, aA3);
            upd(qA1, vA1, mB, lB, aB0, aB1, aB2, aB3);
        }
    }
    if (rem & 1) {
        unsigned o0 = (unsigned)perm_src[e1 - 1] * QKVS + col;
        ushort4 q0 = *(const ushort4*)(QKV + o0);
        ushort4 v0 = *(const ushort4*)(QKV + o0 + 512);
        upd(q0, v0, mA, lA, aA0, aA1, aA2, aA3);
    }

    float mn = fmaxf(mA, mB);
    float scA = (lA > 0.f) ? EXPS(mA - mn) : 0.f;
    float scB = (lB > 0.f) ? EXPS(mB - mn) : 0.f;
    float l = lA * scA + lB * scB;
    float o0 = aA0 * scA + aB0 * scB;
    float o1 = aA1 * scA + aB1 * scB;
    float o2 = aA2 * scA + aB2 * scB;
    float o3 = aA3 * scA + aB3 * scB;
    float inv = (l > 0.f) ? 1.f / l : 0.f;

    ushort4 o;
    o.x = f2bf(o0 * inv); o.y = f2bf(o1 * inv); o.z = f2bf(o2 * inv); o.w = f2bf(o3 * inv);
    *(ushort4*)(attn + (size_t)wid * DIMV + col) = o;
}

// ---------------- launcher ----------------

extern "C" void kernel_launch(void* const* d_in, const int* in_sizes, int n_in,
                              void* d_out, int out_size, void* d_ws, size_t ws_size,
                              hipStream_t stream) {
    const float* x  = (const float*)d_in[0];
    const float* Wq = (const float*)d_in[1];
    const float* bq = (const float*)d_in[2];
    const float* Wk = (const float*)d_in[3];
    const float* bk = (const float*)d_in[4];
    const float* Wv = (const float*)d_in[5];
    const float* bv = (const float*)d_in[6];
    const float* Wo = (const float*)d_in[7];
    const float* bo = (const float*)d_in[8];
    const int* src  = (const int*)d_in[9];
    const int* dst  = (const int*)d_in[10];
    int N = in_sizes[0] / DIMV;
    int E = in_sizes[9];
    float* out = (float*)d_out;

    char* p = (char*)d_ws;
    auto alloc = [&](size_t bytes) {
        char* r = p;
        p += (bytes + 255) & ~(size_t)255;
        return r;
    };
    unsigned short* Wcat = (unsigned short*)alloc((size_t)4 * 65536 * 2);   // fragment-major
    unsigned short* QKV  = (unsigned short*)alloc((size_t)N * QKVS * 2);    // interleaved q|k|v
    unsigned short* attn = (unsigned short*)alloc((size_t)N * DIMV * 2);
    int* deg             = (int*)alloc((size_t)N * 4);
    int* offsets         = (int*)alloc((size_t)(N + 1) * 4);
    int* cursor          = (int*)alloc((size_t)N * 4);
    int* perm_src        = (int*)alloc((size_t)E * 4);
    int* bsum            = (int*)alloc((size_t)1024 * 4);

    int nb = (N + 255) / 256;
    zero_i32<<<nb, 256, 0, stream>>>(deg, N);

    // weight conversion into fragment-major order + fused degree count
    cvt_w_count<<<128, 256, 0, stream>>>(Wq, Wk, Wv, Wo, Wcat, dst, deg, E);

    // scan: deg -> offsets/cursor
    block_sum<<<nb, 256, 0, stream>>>(deg, bsum, N);
    scan_bsum<<<1, 64, 0, stream>>>(bsum, nb);
    scan_final<<<nb, 256, 0, stream>>>(deg, bsum, offsets, cursor, N);

    // QKV projection: x(f32) directly -> interleaved QKV(bf16); leading scatter blocks
    int rblocks = (N + 63) / 64;
    const int SCB = 160;
    gemm_reg<true, false, 6, QKVS, true><<<SCB + rblocks, 256, 0, stream>>>(
        x, Wcat, bq, bk, bv, QKV, N, SCB, src, dst, cursor, perm_src, E);

    node_attn<<<(N + 3) / 4, 256, 0, stream>>>(QKV, offsets, perm_src, attn, N);

    // output projection: attn(bf16) -> out(f32)
    gemm_reg<false, true, 2, DIMV, false><<<rblocks, 256, 0, stream>>>(
        attn, Wcat + (size_t)3 * 65536, bo, bo, bo, out, N, 0,
        nullptr, nullptr, nullptr, nullptr, 0);
}